// Round 4
// baseline (213.596 us; speedup 1.0000x reference)
//
#include <hip/hip_runtime.h>
#include <math.h>

namespace {

constexpr int B = 64;
constexpr int T = 4096;
constexpr int H = 1024;
constexpr float SCALE = 0.03125f;  // 1/sqrt(1024)
constexpr int WPB = 4;             // waves per block (256 threads)

typedef float v4f __attribute__((ext_vector_type(4)));

// Pass 1: single pass over enc_out with online softmax.
// Each wave owns rpw contiguous rows of one batch, processed in PAIRS:
// two independent dot+shuffle-reduce chains interleave (ILP on the LDS
// pipe), one online-max update per pair, and the next pair's 8 loads are
// issued before the current pair's compute (8KB in flight per wave).
__global__ __launch_bounds__(256, 4) void attn_pass1(
    const float* __restrict__ dec_h, const float* __restrict__ enc,
    float* __restrict__ scores, float* __restrict__ acc_ws,
    float* __restrict__ ml_ws, int chunks, int rpw) {
  const int b = blockIdx.y;
  const int wave = threadIdx.x >> 6;
  const int lane = threadIdx.x & 63;
  const int wslot = blockIdx.x * WPB + wave;  // [0, chunks*WPB)
  const int t0 = wslot * rpw;

  // dec fragment: this lane's 16 h-positions (4 strided groups of 4)
  const float* decb = dec_h + (size_t)b * H + lane * 4;
  const v4f d0 = *(const v4f*)(decb);
  const v4f d1 = *(const v4f*)(decb + 256);
  const v4f d2 = *(const v4f*)(decb + 512);
  const v4f d3 = *(const v4f*)(decb + 768);

  v4f a0 = {0.f, 0.f, 0.f, 0.f}, a1 = {0.f, 0.f, 0.f, 0.f};
  v4f a2 = {0.f, 0.f, 0.f, 0.f}, a3 = {0.f, 0.f, 0.f, 0.f};
  float m = -INFINITY;
  float l = 0.f;
  float sv = 0.f;

  // row pointer in v4f units; lane's slice at lane + k*64; row stride 256
  const v4f* rp = (const v4f*)(enc + ((size_t)b * T + t0) * H) + lane;
  float* srow = scores + (size_t)b * T + t0;

  // prologue: rows 0 and 1
  v4f x0 = __builtin_nontemporal_load(rp);
  v4f x1 = __builtin_nontemporal_load(rp + 64);
  v4f x2 = __builtin_nontemporal_load(rp + 128);
  v4f x3 = __builtin_nontemporal_load(rp + 192);
  v4f x4 = __builtin_nontemporal_load(rp + 256);
  v4f x5 = __builtin_nontemporal_load(rp + 320);
  v4f x6 = __builtin_nontemporal_load(rp + 384);
  v4f x7 = __builtin_nontemporal_load(rp + 448);

  for (int r = 0; r < rpw; r += 2) {
    v4f y0, y1, y2, y3, y4, y5, y6, y7;
    if (r + 2 < rpw) {
      const v4f* rq = rp + 512;
      y0 = __builtin_nontemporal_load(rq);
      y1 = __builtin_nontemporal_load(rq + 64);
      y2 = __builtin_nontemporal_load(rq + 128);
      y3 = __builtin_nontemporal_load(rq + 192);
      y4 = __builtin_nontemporal_load(rq + 256);
      y5 = __builtin_nontemporal_load(rq + 320);
      y6 = __builtin_nontemporal_load(rq + 384);
      y7 = __builtin_nontemporal_load(rq + 448);
    }
    rp += 512;

    // two independent dot chains
    float sA0 = x0[0] * d0[0] + x0[1] * d0[1] + x0[2] * d0[2] + x0[3] * d0[3];
    float sA1 = x4[0] * d0[0] + x4[1] * d0[1] + x4[2] * d0[2] + x4[3] * d0[3];
    float sB0 = x1[0] * d1[0] + x1[1] * d1[1] + x1[2] * d1[2] + x1[3] * d1[3];
    float sB1 = x5[0] * d1[0] + x5[1] * d1[1] + x5[2] * d1[2] + x5[3] * d1[3];
    sA0 += x2[0] * d2[0] + x2[1] * d2[1] + x2[2] * d2[2] + x2[3] * d2[3];
    sA1 += x6[0] * d2[0] + x6[1] * d2[1] + x6[2] * d2[2] + x6[3] * d2[3];
    sB0 += x3[0] * d3[0] + x3[1] * d3[1] + x3[2] * d3[2] + x3[3] * d3[3];
    sB1 += x7[0] * d3[0] + x7[1] * d3[1] + x7[2] * d3[2] + x7[3] * d3[3];
    float s0 = sA0 + sB0;
    float s1 = sA1 + sB1;

    // interleaved butterfly reduces (two chains hide each other's latency)
#pragma unroll
    for (int off = 32; off > 0; off >>= 1) {
      s0 += __shfl_xor(s0, off, 64);
      s1 += __shfl_xor(s1, off, 64);
    }
    s0 *= SCALE;
    s1 *= SCALE;

    // bank the wave-uniform scores; one coalesced store per 64 rows
    sv = (lane == (r & 63)) ? s0 : sv;
    sv = (lane == ((r + 1) & 63)) ? s1 : sv;
    if (((r + 1) & 63) == 63) srow[(r & ~63) + lane] = sv;

    // online softmax, one rescale per pair (wave-uniform branch)
    const float mx = fmaxf(s0, s1);
    if (mx > m) {
      const float sc = __expf(m - mx);  // m==-inf first time -> 0
      a0 *= sc; a1 *= sc; a2 *= sc; a3 *= sc;
      l *= sc;
      m = mx;
    }
    const float p0 = __expf(s0 - m);
    const float p1 = __expf(s1 - m);
    l += p0 + p1;
    a0 += p0 * x0 + p1 * x4;
    a1 += p0 * x1 + p1 * x5;
    a2 += p0 * x2 + p1 * x6;
    a3 += p0 * x3 + p1 * x7;

    x0 = y0; x1 = y1; x2 = y2; x3 = y3;
    x4 = y4; x5 = y5; x6 = y6; x7 = y7;
  }

  const size_t pi = (size_t)b * chunks * WPB + wslot;
  float* aw = acc_ws + pi * H + lane * 4;
  *(v4f*)(aw)       = a0;
  *(v4f*)(aw + 256) = a1;
  *(v4f*)(aw + 512) = a2;
  *(v4f*)(aw + 768) = a3;
  if (lane == 0) {
    ml_ws[2 * pi]     = m;
    ml_ws[2 * pi + 1] = l;
  }
}

// Pass 2: per batch, combine np partials -> ctx; normalize weights in place.
__global__ __launch_bounds__(256) void attn_pass2(
    const float* __restrict__ acc_ws, const float* __restrict__ ml_ws,
    float* __restrict__ ctx, float* __restrict__ weights, int np) {
  const int b = blockIdx.x;
  const int tid = threadIdx.x;
  const float* ml = ml_ws + 2 * (size_t)b * np;

  float M = -INFINITY;
  for (int i = 0; i < np; ++i) M = fmaxf(M, ml[2 * i]);
  float L = 0.f;
  for (int i = 0; i < np; ++i) L += ml[2 * i + 1] * __expf(ml[2 * i] - M);
  const float invL = 1.f / L;

  // ctx: 256 threads x 4 floats = 1024
  v4f a = {0.f, 0.f, 0.f, 0.f};
  const float* aw = acc_ws + (size_t)b * np * H + tid * 4;
  for (int i = 0; i < np; ++i) {
    const float w = __expf(ml[2 * i] - M);
    const v4f v = *(const v4f*)(aw + (size_t)i * H);
    a += w * v;
  }
  a *= invL;
  *(v4f*)(ctx + (size_t)b * H + tid * 4) = a;

  float* wrow = weights + (size_t)b * T;
  for (int t = tid; t < T; t += 256) {
    wrow[t] = __expf(wrow[t] - M) * invL;
  }
}

}  // namespace

extern "C" void kernel_launch(void* const* d_in, const int* in_sizes, int n_in,
                              void* d_out, int out_size, void* d_ws,
                              size_t ws_size, hipStream_t stream) {
  const float* dec_h = (const float*)d_in[0];
  const float* enc   = (const float*)d_in[1];
  float* ctx     = (float*)d_out;                  // [B,H]
  float* weights = (float*)d_out + (size_t)B * H;  // [B,T]

  // Largest chunk count whose partial workspace fits in d_ws.
  // need = B*chunks*WPB*(H+2)*4 bytes ~= chunks * 1.05 MB
  int chunks = 16;
  while (chunks > 1 &&
         (size_t)B * chunks * WPB * (H + 2) * sizeof(float) > ws_size)
    chunks >>= 1;
  const int rpw = T / (chunks * WPB);  // 64 at chunks=16 (even, mult of 64)
  const int np = chunks * WPB;

  float* acc_ws = (float*)d_ws;                 // [B*np][H]
  float* ml_ws  = acc_ws + (size_t)B * np * H;  // [B*np][2]

  dim3 g1(chunks, B);
  attn_pass1<<<g1, 256, 0, stream>>>(dec_h, enc, weights, acc_ws, ml_ws,
                                     chunks, rpw);
  attn_pass2<<<B, 256, 0, stream>>>(acc_ws, ml_ws, ctx, weights, np);
}